// Round 1
// baseline (72.006 us; speedup 1.0000x reference)
//
#include <hip/hip_runtime.h>
#include <math.h>

// Problem: B=65536, N=512, N_IN=64, N_OUT=16.
// out[b,j] = act_j(x[b,:64] @ W[:64, 496+j] + bias[496+j]).
//
// R1 theory: kernel part of dur_us (~25us of 70.9) is latency/overhead-bound at
// ~0.8 TB/s, not BW-bound. Fix: 2 tiles/wave (deeper VMEM pipeline, half the
// redundant per-wave W-fragment rebuilds), x loads issued before the L2-hot W
// prologue, nontemporal x loads / out stores (both touched exactly once).

typedef __bf16 bf16x8 __attribute__((ext_vector_type(8)));
typedef float floatx4 __attribute__((ext_vector_type(4)));

#define NN_N 512
#define NN_NIN 64
#define NN_NOUT 16
#define TPW 2   // tiles (16 rows each) per wave

__global__ __launch_bounds__(256) void NeuralNetwork_74466142978489_kernel(
    const float* __restrict__ x,     // [B, 64]
    const float* __restrict__ W,     // [512, 512] row-major
    const float* __restrict__ bias,  // [512]
    const int*   __restrict__ acts,  // [512]
    float* __restrict__ out,         // [B, 16]
    int num_tiles)                   // B / 16
{
    const int lane = threadIdx.x & 63;
    const int wave = (int)((blockIdx.x * blockDim.x + threadIdx.x) >> 6);
    const int m    = lane & 15;   // A-row within tile / output column
    const int quad = lane >> 4;
    const int gcol = NN_N - NN_NOUT + m;       // 496 + m

    const int tile0 = wave * TPW;
    if (tile0 >= num_tiles) return;
    const int ntile = (num_tiles - tile0 < TPW) ? (num_tiles - tile0) : TPW;

    // ---- x loads FIRST: HBM-cold, start the latency clock before the L2-hot
    // W prologue. All TPW*4 float4 loads are independent -> in flight together.
    floatx4 a[TPW][4];
#pragma unroll
    for (int u = 0; u < TPW; ++u) {
        if (u < ntile) {
            const float* row = x + (size_t)((tile0 + u) * 16 + m) * NN_NIN;
#pragma unroll
            for (int t = 0; t < 2; ++t) {
                a[u][2 * t] = __builtin_nontemporal_load(
                    reinterpret_cast<const floatx4*>(row + t * 32 + quad * 8));
                a[u][2 * t + 1] = __builtin_nontemporal_load(
                    reinterpret_cast<const floatx4*>(row + t * 32 + quad * 8 + 4));
            }
        }
    }

    // ---- B fragment: W[k, 496+m] as bf16, k = t*32 + quad*8 + j.
    // W slice is 64x16 floats (4 KB), L2/L3-hot across all waves. Cached loads.
    bf16x8 bfrag0, bfrag1;
#pragma unroll
    for (int j = 0; j < 8; ++j) {
        const int k0 = quad * 8 + j;
        bfrag0[j] = (__bf16)W[k0 * NN_N + gcol];
        bfrag1[j] = (__bf16)W[(k0 + 32) * NN_N + gcol];
    }
    const float bval = bias[gcol];
    const int aid = acts[gcol];

#pragma unroll
    for (int u = 0; u < TPW; ++u) {
        if (u < ntile) {
            floatx4 acc = {bval, bval, bval, bval};
#pragma unroll
            for (int t = 0; t < 2; ++t) {
                bf16x8 af;
#pragma unroll
                for (int e = 0; e < 4; ++e) {
                    af[e]     = (__bf16)a[u][2 * t][e];
                    af[e + 4] = (__bf16)a[u][2 * t + 1][e];
                }
                acc = __builtin_amdgcn_mfma_f32_16x16x32_bf16(
                    af, (t == 0) ? bfrag0 : bfrag1, acc, 0, 0, 0);
            }

            // D layout: col = lane&15, row = quad*4 + r. Per-column activation.
            const int rowbase = (tile0 + u) * 16 + quad * 4;
#pragma unroll
            for (int r = 0; r < 4; ++r) {
                float v = acc[r];
                float y;
                if (aid == 0) {
                    y = 1.0f - 2.0f / (__expf(2.0f * v) + 1.0f);  // stable tanh
                } else if (aid == 1) {
                    y = 1.0f / (1.0f + __expf(-v));
                } else if (aid == 2) {
                    y = v > 0.0f ? v : 0.0f;
                } else if (aid == 3) {
                    y = v > 0.0f ? v : 0.01f * v;
                } else {
                    y = v;
                }
                __builtin_nontemporal_store(
                    y, out + (size_t)(rowbase + r) * NN_NOUT + m);
            }
        }
    }
}

extern "C" void kernel_launch(void* const* d_in, const int* in_sizes, int n_in,
                              void* d_out, int out_size, void* d_ws, size_t ws_size,
                              hipStream_t stream) {
    const float* x    = (const float*)d_in[0];
    const float* W    = (const float*)d_in[1];
    const float* bias = (const float*)d_in[2];
    const int*   acts = (const int*)d_in[3];
    float* out = (float*)d_out;

    const int B = in_sizes[0] / NN_NIN;   // 65536
    const int num_tiles = B / 16;         // 4096

    // 2 tiles per wave: 2048 waves = 512 blocks x 256 threads (8 waves/CU).
    const int block = 256;
    const int waves_per_block = block / 64;
    const int waves = (num_tiles + TPW - 1) / TPW;
    const int grid = (waves + waves_per_block - 1) / waves_per_block;

    NeuralNetwork_74466142978489_kernel<<<grid, block, 0, stream>>>(
        x, W, bias, acts, out, num_tiles);
}